// Round 1
// baseline (5130.600 us; speedup 1.0000x reference)
//
#include <hip/hip_runtime.h>
#include <hip/hip_bf16.h>
#include <cstdint>

// Problem dims (fixed by reference)
#define B_  8
#define C_  256
#define V_  256
#define T_  64
#define CQ_ 32
#define C1_ 128

// ---------------------------------------------------------------------------
// conv_qkv: direct 3x3 SAME conv from x [B,C,V,T] to q/k/v in TRANSPOSED
// layout [B,T,V,Cout] (channel-contiguous for attention / conv_o).
// Block = one (b, v, og) where og indexes a group of 16 output channels over
// the virtual 192-channel (q|k|v) output. 256 threads = 64 t x 4 oi,
// each thread computes 4 consecutive output channels for one t.
// K-loop over input channels in chunks of 16, staging x-slab + weights in LDS.
// ---------------------------------------------------------------------------
__global__ __launch_bounds__(256) void conv_qkv_kernel(
    const float* __restrict__ x, const float* __restrict__ wq,
    const float* __restrict__ wk, const float* __restrict__ wv,
    float* __restrict__ qT, float* __restrict__ kT, float* __restrict__ vT)
{
    __shared__ __align__(16) float xs[16][3][66];   // [c][dv][t padded +-1]
    __shared__ __align__(16) float wls[16][9][16];  // [c][tap][o_local]

    const int tid = threadIdx.x;
    int blk = blockIdx.x;
    const int og = blk % 12; blk /= 12;     // 12 groups of 16 over 192 outputs
    const int v  = blk % V_;
    const int b  = blk / V_;

    const float* wsrc; float* dst; int o_base; int dst_ch;
    if (og < 2)      { wsrc = wq; dst = qT; o_base = og * 16;       dst_ch = CQ_; }
    else if (og < 4) { wsrc = wk; dst = kT; o_base = (og - 2) * 16; dst_ch = CQ_; }
    else             { wsrc = wv; dst = vT; o_base = (og - 4) * 16; dst_ch = C1_; }

    const int t  = tid & 63;
    const int oi = tid >> 6;                // 0..3 -> 4 consecutive o each

    float acc0 = 0.f, acc1 = 0.f, acc2 = 0.f, acc3 = 0.f;

    for (int c0 = 0; c0 < C_; c0 += 16) {
        __syncthreads();
        // stage x chunk: 48 rows (c,dv) x 64 t, as 768 float4 loads
        for (int i = tid; i < 768; i += 256) {
            const int l4 = i & 15;
            const int r  = i >> 4;
            const int dv = r % 3;
            const int c  = r / 3;
            const int vv = v - 1 + dv;
            float4 val = make_float4(0.f, 0.f, 0.f, 0.f);
            if (vv >= 0 && vv < V_)
                val = *(const float4*)&x[(((size_t)b * C_ + (c0 + c)) * V_ + vv) * T_ + l4 * 4];
            float* p = &xs[c][dv][1 + l4 * 4];
            p[0] = val.x; p[1] = val.y; p[2] = val.z; p[3] = val.w;
        }
        if (tid < 48) {  // zero t-borders
            const int dv = tid % 3, c = tid / 3;
            xs[c][dv][0] = 0.f; xs[c][dv][65] = 0.f;
        }
        // stage weights: one (o_l, c_l) per thread, 9 taps each
        {
            const int o_l = tid >> 4, c_l = tid & 15;
            const float* wp = &wsrc[(((size_t)(o_base + o_l)) * C_ + (c0 + c_l)) * 9];
            #pragma unroll
            for (int tap = 0; tap < 9; tap++) wls[c_l][tap][o_l] = wp[tap];
        }
        __syncthreads();

        #pragma unroll 4
        for (int c = 0; c < 16; c++) {
            float xv[9];
            #pragma unroll
            for (int dv = 0; dv < 3; dv++)
                #pragma unroll
                for (int dt = 0; dt < 3; dt++)
                    xv[dv * 3 + dt] = xs[c][dv][t + dt];
            #pragma unroll
            for (int tap = 0; tap < 9; tap++) {
                const float4 w4 = *(const float4*)&wls[c][tap][oi * 4];  // wave-uniform broadcast
                acc0 = fmaf(xv[tap], w4.x, acc0);
                acc1 = fmaf(xv[tap], w4.y, acc1);
                acc2 = fmaf(xv[tap], w4.z, acc2);
                acc3 = fmaf(xv[tap], w4.w, acc3);
            }
        }
    }
    const size_t n = ((size_t)b * T_ + t) * V_ + v;
    *(float4*)&dst[n * dst_ch + o_base + oi * 4] = make_float4(acc0, acc1, acc2, acc3);
}

// ---------------------------------------------------------------------------
// attn: one block per (b,t) slice. q,k,v,av slices are [V, C] channel-
// contiguous. K slice (32KB) in LDS, own q row in registers.
// Pass 0: online softmax (m,l). Passes 1,2: recompute scores, accumulate
// 64 output channels each (v rows read via broadcast global float4 loads).
// ---------------------------------------------------------------------------
__global__ __launch_bounds__(256) void attn_kernel(
    const float* __restrict__ qT, const float* __restrict__ kT,
    const float* __restrict__ vT, float* __restrict__ avT)
{
    __shared__ __align__(16) float ks[256 * 32];
    const int tid = threadIdx.x;       // = row v of this slice
    const int bt  = blockIdx.x;        // b*T + t

    // stage K slice, coalesced + conflict-free
    {
        const float4* kp = (const float4*)&kT[(size_t)bt * 256 * 32];
        float4* ks4 = (float4*)ks;
        for (int i = tid; i < 2048; i += 256) ks4[i] = kp[i];
    }
    float q[32];
    {
        const float4* qp = (const float4*)&qT[((size_t)bt * 256 + tid) * 32];
        float4* q4 = (float4*)q;
        #pragma unroll
        for (int j = 0; j < 8; j++) q4[j] = qp[j];
    }
    __syncthreads();

    // pass 0: online max/sum
    float m = -1e30f, l = 0.f;
    for (int u = 0; u < 256; u++) {
        float s = 0.f;
        const float* kr = &ks[u * 32];
        #pragma unroll
        for (int j = 0; j < 32; j++) s = fmaf(q[j], kr[j], s);
        const float mn = fmaxf(m, s);
        l = l * __expf(m - mn) + __expf(s - mn);
        m = mn;
    }
    const float inv_l = 1.f / l;

    #pragma unroll
    for (int half = 0; half < 2; half++) {
        float acc[64];
        #pragma unroll
        for (int c = 0; c < 64; c++) acc[c] = 0.f;
        for (int u = 0; u < 256; u++) {
            float s = 0.f;
            const float* kr = &ks[u * 32];
            #pragma unroll
            for (int j = 0; j < 32; j++) s = fmaf(q[j], kr[j], s);
            const float p = __expf(s - m) * inv_l;
            const float4* vp = (const float4*)&vT[((size_t)bt * 256 + u) * C1_ + half * 64];
            #pragma unroll
            for (int c4 = 0; c4 < 16; c4++) {
                const float4 vv = vp[c4];  // wave-uniform broadcast load
                acc[c4 * 4 + 0] = fmaf(p, vv.x, acc[c4 * 4 + 0]);
                acc[c4 * 4 + 1] = fmaf(p, vv.y, acc[c4 * 4 + 1]);
                acc[c4 * 4 + 2] = fmaf(p, vv.z, acc[c4 * 4 + 2]);
                acc[c4 * 4 + 3] = fmaf(p, vv.w, acc[c4 * 4 + 3]);
            }
        }
        float4* op = (float4*)&avT[((size_t)bt * 256 + tid) * C1_ + half * 64];
        #pragma unroll
        for (int c4 = 0; c4 < 16; c4++)
            op[c4] = make_float4(acc[c4 * 4], acc[c4 * 4 + 1], acc[c4 * 4 + 2], acc[c4 * 4 + 3]);
    }
}

// ---------------------------------------------------------------------------
// conv_o: 3x3 SAME conv from avT [B,T,V,C1] (channel-major) to out [B,C,V,T],
// fused residual out = x + sigma * conv. Same block structure as conv_qkv:
// block = (b, v, og of 16 output channels), K-loop chunks of 16 over C1=128.
// ---------------------------------------------------------------------------
__global__ __launch_bounds__(256) void conv_o_kernel(
    const float* __restrict__ avT, const float* __restrict__ wo,
    const float* __restrict__ x, const float* __restrict__ sigma,
    float* __restrict__ out)
{
    __shared__ __align__(16) float xs[16][3][66];
    __shared__ __align__(16) float wls[16][9][16];

    const int tid = threadIdx.x;
    int blk = blockIdx.x;
    const int og = blk % 16; blk /= 16;   // 16 groups of 16 over 256 outputs
    const int v  = blk % V_;
    const int b  = blk / V_;

    const int t  = tid & 63;
    const int oi = tid >> 6;

    float acc0 = 0.f, acc1 = 0.f, acc2 = 0.f, acc3 = 0.f;

    for (int c0 = 0; c0 < C1_; c0 += 16) {
        __syncthreads();
        // stage avT chunk: rows (dv, tt) x 16 c; transpose to [c][dv][tt]
        for (int i = tid; i < 792; i += 256) {
            const int lane = i & 3;
            const int r  = i >> 2;
            const int tt = r % 66;
            const int dv = r / 66;
            const int vv = v - 1 + dv;
            const int ts = tt - 1;
            float4 val = make_float4(0.f, 0.f, 0.f, 0.f);
            if (vv >= 0 && vv < V_ && ts >= 0 && ts < T_)
                val = *(const float4*)&avT[(((size_t)b * T_ + ts) * V_ + vv) * C1_ + c0 + lane * 4];
            const int cc = lane * 4;
            xs[cc + 0][dv][tt] = val.x;
            xs[cc + 1][dv][tt] = val.y;
            xs[cc + 2][dv][tt] = val.z;
            xs[cc + 3][dv][tt] = val.w;
        }
        {
            const int o_l = tid >> 4, c_l = tid & 15;
            const float* wp = &wo[(((size_t)(og * 16 + o_l)) * C1_ + (c0 + c_l)) * 9];
            #pragma unroll
            for (int tap = 0; tap < 9; tap++) wls[c_l][tap][o_l] = wp[tap];
        }
        __syncthreads();

        #pragma unroll 4
        for (int c = 0; c < 16; c++) {
            float xv[9];
            #pragma unroll
            for (int dv = 0; dv < 3; dv++)
                #pragma unroll
                for (int dt = 0; dt < 3; dt++)
                    xv[dv * 3 + dt] = xs[c][dv][t + dt];
            #pragma unroll
            for (int tap = 0; tap < 9; tap++) {
                const float4 w4 = *(const float4*)&wls[c][tap][oi * 4];
                acc0 = fmaf(xv[tap], w4.x, acc0);
                acc1 = fmaf(xv[tap], w4.y, acc1);
                acc2 = fmaf(xv[tap], w4.z, acc2);
                acc3 = fmaf(xv[tap], w4.w, acc3);
            }
        }
    }
    const float sg = sigma[0];
    const float a[4] = {acc0, acc1, acc2, acc3};
    #pragma unroll
    for (int j = 0; j < 4; j++) {
        const int o = og * 16 + oi * 4 + j;
        const size_t idx = (((size_t)b * C_ + o) * V_ + v) * T_ + t;
        out[idx] = x[idx] + sg * a[j];   // coalesced over t within each o
    }
}

// ---------------------------------------------------------------------------
extern "C" void kernel_launch(void* const* d_in, const int* in_sizes, int n_in,
                              void* d_out, int out_size, void* d_ws, size_t ws_size,
                              hipStream_t stream)
{
    const float* x     = (const float*)d_in[0];
    const float* wq    = (const float*)d_in[1];
    const float* wk    = (const float*)d_in[2];
    const float* wv    = (const float*)d_in[3];
    const float* wo    = (const float*)d_in[4];
    const float* sigma = (const float*)d_in[5];
    float* out = (float*)d_out;

    // workspace layout (all fp32): qT/kT [B,T,V,32], vT/avT [B,T,V,128]
    // total = (2*4.19M + 2*16.78M) * 4B = 167.8 MB
    float* qT  = (float*)d_ws;
    float* kT  = qT + (size_t)B_ * T_ * V_ * CQ_;
    float* vT  = kT + (size_t)B_ * T_ * V_ * CQ_;
    float* avT = vT + (size_t)B_ * T_ * V_ * C1_;

    conv_qkv_kernel<<<B_ * V_ * 12, 256, 0, stream>>>(x, wq, wk, wv, qT, kT, vT);
    attn_kernel<<<B_ * T_, 256, 0, stream>>>(qT, kT, vT, avT);
    conv_o_kernel<<<B_ * V_ * 16, 256, 0, stream>>>(avT, wo, x, sigma, out);
}

// Round 2
// 1168.640 us; speedup vs baseline: 4.3902x; 4.3902x over previous
//
#include <hip/hip_runtime.h>
#include <hip/hip_bf16.h>
#include <cstdint>

// Problem dims (fixed by reference)
#define B_  8
#define C_  256
#define V_  256
#define T_  64
#define CQ_ 32
#define C1_ 128

typedef float  floatx4 __attribute__((ext_vector_type(4)));
typedef __bf16 bf16x8  __attribute__((ext_vector_type(8)));

static __device__ __forceinline__ ushort f2bf(float f) {
    union { float f; uint32_t u; } cv; cv.f = f;
    const uint32_t u = cv.u;
    return (ushort)((u + 0x7FFFu + ((u >> 16) & 1u)) >> 16);   // RNE
}
static __device__ __forceinline__ float bf2f(ushort u) {
    union { uint32_t u; float f; } cv; cv.u = ((uint32_t)u) << 16;
    return cv.f;
}
// unpack two bf16 from a packed uint
static __device__ __forceinline__ void bf2x(uint32_t p, float& f0, float& f1) {
    union { uint32_t u; float f; } a, b;
    a.u = p << 16; b.u = p & 0xffff0000u;
    f0 = a.f; f1 = b.f;
}

// ---------------------------------------------------------------------------
// transpose_x: x fp32 [B,C,V,T] -> xT bf16 [B,V,T,C] (channel-contiguous)
// Block = (b,v). LDS tile transpose so both global read and write coalesce.
// ---------------------------------------------------------------------------
__global__ __launch_bounds__(256) void transpose_x(
    const float* __restrict__ x, ushort* __restrict__ xT)
{
    __shared__ float xs[256 * 65];   // [c][t], row pad 65 -> conflict-free
    const int tid = threadIdx.x;
    const int v = blockIdx.x & 255;
    const int b = blockIdx.x >> 8;

    for (int i = tid; i < 16384; i += 256) {
        const int t = i & 63, c = i >> 6;
        xs[c * 65 + t] = x[(((size_t)b * C_ + c) * V_ + v) * T_ + t];
    }
    __syncthreads();
    for (int i = tid; i < 16384; i += 256) {
        const int c = i & 255, t = i >> 8;
        xT[(((size_t)b * V_ + v) * T_ + t) * C_ + c] = f2bf(xs[c * 65 + t]);
    }
}

// ---------------------------------------------------------------------------
// pack_weights: wq/wk/wv -> Wqkv bf16 [192][2304], wo -> Wo bf16 [256][1152].
// K index ordered (c_chunk, tap, c_within32) so one staged x-chunk serves
// 9 consecutive K-steps (taps).
// ---------------------------------------------------------------------------
__global__ __launch_bounds__(256) void pack_weights(
    const float* __restrict__ wq, const float* __restrict__ wk,
    const float* __restrict__ wv, const float* __restrict__ wo,
    ushort* __restrict__ Wqkv, ushort* __restrict__ Wo)
{
    const int r = blockIdx.x;
    const int tid = threadIdx.x;
    const float* src; ushort* dst; int Klen;
    if (r < 192) {
        if (r < 32)      src = wq + (size_t)r * 2304;
        else if (r < 64) src = wk + (size_t)(r - 32) * 2304;
        else             src = wv + (size_t)(r - 64) * 2304;
        dst = Wqkv + (size_t)r * 2304; Klen = 2304;
    } else {
        src = wo + (size_t)(r - 192) * 1152;
        dst = Wo + (size_t)(r - 192) * 1152; Klen = 1152;
    }
    for (int k = tid; k < Klen; k += 256) {
        const int cc = k / 288, rem = k % 288;
        const int tap = rem >> 5, ci = rem & 31;
        const int c = cc * 32 + ci;
        dst[k] = f2bf(src[c * 9 + tap]);
    }
}

// ---------------------------------------------------------------------------
// conv_qkv_mfma: implicit-GEMM 3x3 conv, bf16 MFMA 16x16x32.
// Block = (b, v2 of 2 v-rows, og of 64 output channels over packed 192).
// Block tile M=64 x N=128(2v x 64t), 4 waves of 32x64 (2x4 16x16 frags).
// K loop: 8 chunks of 32 channels; per chunk stage x-tile (4 v-rows with
// halo x 66 t padded x 32c, pad row->40) + weights (64 x 288, pad->296),
// then 9 taps x 8 MFMAs per wave.
// Outputs qb/kb/vb bf16 [B,V,T,Cout].
// ---------------------------------------------------------------------------
__global__ __launch_bounds__(256) void conv_qkv_mfma(
    const ushort* __restrict__ xT, const ushort* __restrict__ Wqkv,
    ushort* __restrict__ qb, ushort* __restrict__ kb, ushort* __restrict__ vb)
{
    __shared__ __align__(16) ushort Bs[4 * 66 * 40];   // 21.1 KB
    __shared__ __align__(16) ushort As[64 * 296];      // 37.9 KB

    const int tid  = threadIdx.x;
    const int lane = tid & 63;
    const int wave = tid >> 6;
    const int wave_m = (wave >> 1) * 32;
    const int wave_n = (wave & 1) * 64;
    const int nl = lane & 15;       // m/n within 16-tile
    const int q8 = lane >> 4;       // k-block (8 bf16 each)

    int idx = blockIdx.x;
    const int og = idx % 3; idx /= 3;
    const int v2 = idx & 127;
    const int b  = idx >> 7;
    const int v0 = v2 * 2;

    floatx4 acc[2][4];
    #pragma unroll
    for (int i = 0; i < 2; i++)
        #pragma unroll
        for (int j = 0; j < 4; j++) acc[i][j] = (floatx4)0.f;

    const int rr = tid >> 6, ts = tid & 63;   // staging roles
    const int vsrc = v0 - 1 + rr;
    const int ar = tid >> 2, sub = tid & 3;

    for (int cc = 0; cc < 8; cc++) {
        const int c0 = cc * 32;
        __syncthreads();
        // ---- stage B (x tile) ----
        {
            ushort* bdst = &Bs[(rr * 66 + 1 + ts) * 40];
            if (vsrc >= 0 && vsrc < V_) {
                const ushort* src = &xT[(((size_t)b * V_ + vsrc) * T_ + ts) * C_ + c0];
                *(uint4*)(bdst + 0)  = *(const uint4*)(src + 0);
                *(uint4*)(bdst + 8)  = *(const uint4*)(src + 8);
                *(uint4*)(bdst + 16) = *(const uint4*)(src + 16);
                *(uint4*)(bdst + 24) = *(const uint4*)(src + 24);
            } else {
                const uint4 z = {0u, 0u, 0u, 0u};
                *(uint4*)(bdst + 0) = z; *(uint4*)(bdst + 8) = z;
                *(uint4*)(bdst + 16) = z; *(uint4*)(bdst + 24) = z;
            }
            if (tid < 8) {  // zero t-halo columns
                const int r2 = tid >> 1, side = (tid & 1) * 65;
                ushort* zp = &Bs[(r2 * 66 + side) * 40];
                const uint4 z = {0u, 0u, 0u, 0u};
                *(uint4*)(zp + 0) = z; *(uint4*)(zp + 8) = z;
                *(uint4*)(zp + 16) = z; *(uint4*)(zp + 24) = z;
            }
        }
        // ---- stage A (weights) ----
        {
            const ushort* asrc = &Wqkv[(size_t)(og * 64 + ar) * 2304 + cc * 288];
            ushort* adst = &As[ar * 296];
            #pragma unroll
            for (int j = 0; j < 9; j++) {
                const int w8 = (sub + j * 4) * 8;
                *(uint4*)(adst + w8) = *(const uint4*)(asrc + w8);
            }
        }
        __syncthreads();

        // ---- compute: 9 taps ----
        #pragma unroll
        for (int tap = 0; tap < 9; tap++) {
            const int dv = tap / 3, dt = tap % 3;
            const bf16x8 a0 = *(const bf16x8*)&As[(wave_m + nl) * 296 + tap * 32 + q8 * 8];
            const bf16x8 a1 = *(const bf16x8*)&As[(wave_m + 16 + nl) * 296 + tap * 32 + q8 * 8];
            #pragma unroll
            for (int nt = 0; nt < 4; nt++) {
                const int n0 = wave_n + nt * 16;
                const int vv = n0 >> 6, tt0 = n0 & 63;
                const bf16x8 bf = *(const bf16x8*)
                    &Bs[((vv + dv) * 66 + tt0 + nl + dt) * 40 + q8 * 8];
                acc[0][nt] = __builtin_amdgcn_mfma_f32_16x16x32_bf16(a0, bf, acc[0][nt], 0, 0, 0);
                acc[1][nt] = __builtin_amdgcn_mfma_f32_16x16x32_bf16(a1, bf, acc[1][nt], 0, 0, 0);
            }
        }
    }

    // ---- epilogue: C/D layout col=lane&15 (n), row=(lane>>4)*4+reg (m) ----
    #pragma unroll
    for (int mt = 0; mt < 2; mt++) {
        const int g0 = og * 64 + wave_m + mt * 16 + q8 * 4;  // packed out-row of reg0
        ushort* buf; int cbase, Cb;
        if (g0 < 32)      { buf = qb; cbase = g0;      Cb = CQ_; }
        else if (g0 < 64) { buf = kb; cbase = g0 - 32; Cb = CQ_; }
        else              { buf = vb; cbase = g0 - 64; Cb = C1_; }
        #pragma unroll
        for (int nt = 0; nt < 4; nt++) {
            const int n = wave_n + nt * 16 + nl;
            const int vv = n >> 6, tt = n & 63;
            const floatx4 A = acc[mt][nt];
            ushort4 o;
            o.x = f2bf(A[0]); o.y = f2bf(A[1]); o.z = f2bf(A[2]); o.w = f2bf(A[3]);
            *(ushort4*)&buf[(((size_t)b * V_ + v0 + vv) * T_ + tt) * Cb + cbase] = o;
        }
    }
}

// ---------------------------------------------------------------------------
// conv_o_mfma: same structure, input avT bf16 [B,V,T,128], K=1152 (4 chunks),
// M=256 over 4 og. Epilogue: out fp32 [B,C,V,T] = x + sigma*conv (coalesced
// over t within each lane-quad).
// ---------------------------------------------------------------------------
__global__ __launch_bounds__(256) void conv_o_mfma(
    const ushort* __restrict__ avT, const ushort* __restrict__ Wo,
    const float* __restrict__ x, const float* __restrict__ sigma,
    float* __restrict__ out)
{
    __shared__ __align__(16) ushort Bs[4 * 66 * 40];
    __shared__ __align__(16) ushort As[64 * 296];

    const int tid  = threadIdx.x;
    const int lane = tid & 63;
    const int wave = tid >> 6;
    const int wave_m = (wave >> 1) * 32;
    const int wave_n = (wave & 1) * 64;
    const int nl = lane & 15;
    const int q8 = lane >> 4;

    int idx = blockIdx.x;
    const int og = idx & 3; idx >>= 2;
    const int v2 = idx & 127;
    const int b  = idx >> 7;
    const int v0 = v2 * 2;

    floatx4 acc[2][4];
    #pragma unroll
    for (int i = 0; i < 2; i++)
        #pragma unroll
        for (int j = 0; j < 4; j++) acc[i][j] = (floatx4)0.f;

    const int rr = tid >> 6, ts = tid & 63;
    const int vsrc = v0 - 1 + rr;
    const int ar = tid >> 2, sub = tid & 3;

    for (int cc = 0; cc < 4; cc++) {
        const int c0 = cc * 32;
        __syncthreads();
        {
            ushort* bdst = &Bs[(rr * 66 + 1 + ts) * 40];
            if (vsrc >= 0 && vsrc < V_) {
                const ushort* src = &avT[(((size_t)b * V_ + vsrc) * T_ + ts) * C1_ + c0];
                *(uint4*)(bdst + 0)  = *(const uint4*)(src + 0);
                *(uint4*)(bdst + 8)  = *(const uint4*)(src + 8);
                *(uint4*)(bdst + 16) = *(const uint4*)(src + 16);
                *(uint4*)(bdst + 24) = *(const uint4*)(src + 24);
            } else {
                const uint4 z = {0u, 0u, 0u, 0u};
                *(uint4*)(bdst + 0) = z; *(uint4*)(bdst + 8) = z;
                *(uint4*)(bdst + 16) = z; *(uint4*)(bdst + 24) = z;
            }
            if (tid < 8) {
                const int r2 = tid >> 1, side = (tid & 1) * 65;
                ushort* zp = &Bs[(r2 * 66 + side) * 40];
                const uint4 z = {0u, 0u, 0u, 0u};
                *(uint4*)(zp + 0) = z; *(uint4*)(zp + 8) = z;
                *(uint4*)(zp + 16) = z; *(uint4*)(zp + 24) = z;
            }
        }
        {
            const ushort* asrc = &Wo[(size_t)(og * 64 + ar) * 1152 + cc * 288];
            ushort* adst = &As[ar * 296];
            #pragma unroll
            for (int j = 0; j < 9; j++) {
                const int w8 = (sub + j * 4) * 8;
                *(uint4*)(adst + w8) = *(const uint4*)(asrc + w8);
            }
        }
        __syncthreads();

        #pragma unroll
        for (int tap = 0; tap < 9; tap++) {
            const int dv = tap / 3, dt = tap % 3;
            const bf16x8 a0 = *(const bf16x8*)&As[(wave_m + nl) * 296 + tap * 32 + q8 * 8];
            const bf16x8 a1 = *(const bf16x8*)&As[(wave_m + 16 + nl) * 296 + tap * 32 + q8 * 8];
            #pragma unroll
            for (int nt = 0; nt < 4; nt++) {
                const int n0 = wave_n + nt * 16;
                const int vv = n0 >> 6, tt0 = n0 & 63;
                const bf16x8 bf = *(const bf16x8*)
                    &Bs[((vv + dv) * 66 + tt0 + nl + dt) * 40 + q8 * 8];
                acc[0][nt] = __builtin_amdgcn_mfma_f32_16x16x32_bf16(a0, bf, acc[0][nt], 0, 0, 0);
                acc[1][nt] = __builtin_amdgcn_mfma_f32_16x16x32_bf16(a1, bf, acc[1][nt], 0, 0, 0);
            }
        }
    }

    const float sg = sigma[0];
    #pragma unroll
    for (int mt = 0; mt < 2; mt++) {
        const int cb = og * 64 + wave_m + mt * 16 + q8 * 4;
        #pragma unroll
        for (int nt = 0; nt < 4; nt++) {
            const int n = wave_n + nt * 16 + nl;
            const int vv = n >> 6, tt = n & 63;
            const floatx4 A = acc[mt][nt];
            #pragma unroll
            for (int r = 0; r < 4; r++) {
                const size_t o = (((size_t)b * C_ + cb + r) * V_ + (v0 + vv)) * T_ + tt;
                out[o] = x[o] + sg * A[r];
            }
        }
    }
}

// ---------------------------------------------------------------------------
// attn: scalar fp32 softmax-attention per (b,t) slice over v. Inputs bf16
// channel-major [B,V,T,C]. K slice + V half-slice staged to LDS as fp32.
// Pass 0: online max/sum. Two PV passes of 64 channels each.
// ---------------------------------------------------------------------------
__global__ __launch_bounds__(256) void attn_kernel(
    const ushort* __restrict__ qb, const ushort* __restrict__ kb,
    const ushort* __restrict__ vb, ushort* __restrict__ avT)
{
    __shared__ float ksh[256 * 33];   // 33.8 KB, row pad 33 -> conflict-free
    __shared__ float vsh[256 * 67];   // 68.6 KB

    const int tid = threadIdx.x;      // = row v (and staging row u)
    const int bt  = blockIdx.x;
    const int b = bt >> 6, t = bt & 63;

    // stage K slice (fp32 in LDS)
    {
        const ushort* kp = &kb[(((size_t)b * V_ + tid) * T_ + t) * CQ_];
        #pragma unroll
        for (int j4 = 0; j4 < 4; j4++) {
            const uint4 w = *(const uint4*)(kp + j4 * 8);
            float* d = &ksh[tid * 33 + j4 * 8];
            bf2x(w.x, d[0], d[1]); bf2x(w.y, d[2], d[3]);
            bf2x(w.z, d[4], d[5]); bf2x(w.w, d[6], d[7]);
        }
    }
    // own q row in registers
    float q[32];
    {
        const ushort* qp = &qb[(((size_t)b * V_ + tid) * T_ + t) * CQ_];
        #pragma unroll
        for (int j4 = 0; j4 < 4; j4++) {
            const uint4 w = *(const uint4*)(qp + j4 * 8);
            float* d = &q[j4 * 8];
            bf2x(w.x, d[0], d[1]); bf2x(w.y, d[2], d[3]);
            bf2x(w.z, d[4], d[5]); bf2x(w.w, d[6], d[7]);
        }
    }
    // stage V half 0
    {
        const ushort* vp = &vb[(((size_t)b * V_ + tid) * T_ + t) * C1_];
        #pragma unroll
        for (int j4 = 0; j4 < 8; j4++) {
            const uint4 w = *(const uint4*)(vp + j4 * 8);
            float* d = &vsh[tid * 67 + j4 * 8];
            bf2x(w.x, d[0], d[1]); bf2x(w.y, d[2], d[3]);
            bf2x(w.z, d[4], d[5]); bf2x(w.w, d[6], d[7]);
        }
    }
    __syncthreads();

    // pass 0: online max / sum
    float m = -1e30f, l = 0.f;
    for (int u = 0; u < 256; u++) {
        const float* kr = &ksh[u * 33];
        float s = 0.f;
        #pragma unroll
        for (int j = 0; j < 32; j++) s = fmaf(q[j], kr[j], s);
        const float mn = fmaxf(m, s);
        l = l * __expf(m - mn) + __expf(s - mn);
        m = mn;
    }
    const float inv_l = 1.f / l;

    #pragma unroll 1
    for (int half = 0; half < 2; half++) {
        if (half == 1) {
            __syncthreads();   // protect half-0 reads
            const ushort* vp = &vb[(((size_t)b * V_ + tid) * T_ + t) * C1_ + 64];
            #pragma unroll
            for (int j4 = 0; j4 < 8; j4++) {
                const uint4 w = *(const uint4*)(vp + j4 * 8);
                float* d = &vsh[tid * 67 + j4 * 8];
                bf2x(w.x, d[0], d[1]); bf2x(w.y, d[2], d[3]);
                bf2x(w.z, d[4], d[5]); bf2x(w.w, d[6], d[7]);
            }
            __syncthreads();
        }
        float acc[64];
        #pragma unroll
        for (int j = 0; j < 64; j++) acc[j] = 0.f;
        for (int u = 0; u < 256; u++) {
            const float* kr = &ksh[u * 33];
            float s = 0.f;
            #pragma unroll
            for (int j = 0; j < 32; j++) s = fmaf(q[j], kr[j], s);
            const float p = __expf(s - m) * inv_l;
            const float* vr = &vsh[u * 67];
            #pragma unroll
            for (int j = 0; j < 64; j++) acc[j] = fmaf(p, vr[j], acc[j]);
        }
        // write 64 bf16 (128B contiguous per thread)
        ushort* op = &avT[(((size_t)b * V_ + tid) * T_ + t) * C1_ + half * 64];
        #pragma unroll
        for (int j4 = 0; j4 < 8; j4++) {
            uint4 o;
            o.x = (uint)f2bf(acc[j4 * 8 + 0]) | ((uint)f2bf(acc[j4 * 8 + 1]) << 16);
            o.y = (uint)f2bf(acc[j4 * 8 + 2]) | ((uint)f2bf(acc[j4 * 8 + 3]) << 16);
            o.z = (uint)f2bf(acc[j4 * 8 + 4]) | ((uint)f2bf(acc[j4 * 8 + 5]) << 16);
            o.w = (uint)f2bf(acc[j4 * 8 + 6]) | ((uint)f2bf(acc[j4 * 8 + 7]) << 16);
            *(uint4*)(op + j4 * 8) = o;
        }
    }
}

// ---------------------------------------------------------------------------
extern "C" void kernel_launch(void* const* d_in, const int* in_sizes, int n_in,
                              void* d_out, int out_size, void* d_ws, size_t ws_size,
                              hipStream_t stream)
{
    const float* x     = (const float*)d_in[0];
    const float* wq    = (const float*)d_in[1];
    const float* wk    = (const float*)d_in[2];
    const float* wv    = (const float*)d_in[3];
    const float* wo    = (const float*)d_in[4];
    const float* sigma = (const float*)d_in[5];
    float* out = (float*)d_out;

    // workspace (bf16/ushort), total ~152.5 MB
    ushort* ws   = (ushort*)d_ws;
    ushort* xT   = ws;  ws += (size_t)B_ * V_ * T_ * C_;    // 33,554,432
    ushort* qb   = ws;  ws += (size_t)B_ * V_ * T_ * CQ_;   //  4,194,304
    ushort* kb   = ws;  ws += (size_t)B_ * V_ * T_ * CQ_;   //  4,194,304
    ushort* vb   = ws;  ws += (size_t)B_ * V_ * T_ * C1_;   // 16,777,216
    ushort* avT  = ws;  ws += (size_t)B_ * V_ * T_ * C1_;   // 16,777,216
    ushort* Wqkv = ws;  ws += 192 * 2304;
    ushort* Wo   = ws;  ws += 256 * 1152;

    transpose_x <<<B_ * V_, 256, 0, stream>>>(x, xT);
    pack_weights<<<448, 256, 0, stream>>>(wq, wk, wv, wo, Wqkv, Wo);
    conv_qkv_mfma<<<B_ * 128 * 3, 256, 0, stream>>>(xT, Wqkv, qb, kb, vb);
    attn_kernel <<<B_ * T_, 256, 0, stream>>>(qb, kb, vb, avT);
    conv_o_mfma <<<B_ * 128 * 4, 256, 0, stream>>>(avT, Wo, x, sigma, out);
}

// Round 3
// 579.734 us; speedup vs baseline: 8.8499x; 2.0158x over previous
//
#include <hip/hip_runtime.h>
#include <hip/hip_bf16.h>
#include <cstdint>

// Problem dims (fixed by reference)
#define B_  8
#define C_  256
#define V_  256
#define T_  64
#define CQ_ 32
#define C1_ 128

typedef float  floatx4 __attribute__((ext_vector_type(4)));
typedef __bf16 bf16x8  __attribute__((ext_vector_type(8)));

static __device__ __forceinline__ ushort f2bf(float f) {
    union { float f; uint32_t u; } cv; cv.f = f;
    const uint32_t u = cv.u;
    return (ushort)((u + 0x7FFFu + ((u >> 16) & 1u)) >> 16);   // RNE
}
// unpack two bf16 from a packed uint
static __device__ __forceinline__ void bf2x(uint32_t p, float& f0, float& f1) {
    union { uint32_t u; float f; } a, b;
    a.u = p << 16; b.u = p & 0xffff0000u;
    f0 = a.f; f1 = b.f;
}

// ---------------------------------------------------------------------------
// transpose_x: x fp32 [B,C,V,T] -> xT bf16 [B,V,T,C] (channel-contiguous)
// ---------------------------------------------------------------------------
__global__ __launch_bounds__(256) void transpose_x(
    const float* __restrict__ x, ushort* __restrict__ xT)
{
    __shared__ float xs[256 * 65];   // [c][t], row pad 65 -> conflict-free
    const int tid = threadIdx.x;
    const int v = blockIdx.x & 255;
    const int b = blockIdx.x >> 8;

    for (int i = tid; i < 16384; i += 256) {
        const int t = i & 63, c = i >> 6;
        xs[c * 65 + t] = x[(((size_t)b * C_ + c) * V_ + v) * T_ + t];
    }
    __syncthreads();
    for (int i = tid; i < 16384; i += 256) {
        const int c = i & 255, t = i >> 8;
        xT[(((size_t)b * V_ + v) * T_ + t) * C_ + c] = f2bf(xs[c * 65 + t]);
    }
}

// ---------------------------------------------------------------------------
// pack_weights: wq/wk/wv -> Wqkv bf16 [192][2304], wo -> Wo bf16 [256][1152].
// K order: (c_chunk, tap, c_within32).
// ---------------------------------------------------------------------------
__global__ __launch_bounds__(256) void pack_weights(
    const float* __restrict__ wq, const float* __restrict__ wk,
    const float* __restrict__ wv, const float* __restrict__ wo,
    ushort* __restrict__ Wqkv, ushort* __restrict__ Wo)
{
    const int r = blockIdx.x;
    const int tid = threadIdx.x;
    const float* src; ushort* dst; int Klen;
    if (r < 192) {
        if (r < 32)      src = wq + (size_t)r * 2304;
        else if (r < 64) src = wk + (size_t)(r - 32) * 2304;
        else             src = wv + (size_t)(r - 64) * 2304;
        dst = Wqkv + (size_t)r * 2304; Klen = 2304;
    } else {
        src = wo + (size_t)(r - 192) * 1152;
        dst = Wo + (size_t)(r - 192) * 1152; Klen = 1152;
    }
    for (int k = tid; k < Klen; k += 256) {
        const int cc = k / 288, rem = k % 288;
        const int tap = rem >> 5, ci = rem & 31;
        const int c = cc * 32 + ci;
        dst[k] = f2bf(src[c * 9 + tap]);
    }
}

// ---------------------------------------------------------------------------
// conv_qkv_mfma: implicit-GEMM 3x3 conv, bf16 MFMA 16x16x32 (unchanged R2).
// ---------------------------------------------------------------------------
__global__ __launch_bounds__(256) void conv_qkv_mfma(
    const ushort* __restrict__ xT, const ushort* __restrict__ Wqkv,
    ushort* __restrict__ qb, ushort* __restrict__ kb, ushort* __restrict__ vb)
{
    __shared__ __align__(16) ushort Bs[4 * 66 * 40];   // 21.1 KB
    __shared__ __align__(16) ushort As[64 * 296];      // 37.9 KB

    const int tid  = threadIdx.x;
    const int lane = tid & 63;
    const int wave = tid >> 6;
    const int wave_m = (wave >> 1) * 32;
    const int wave_n = (wave & 1) * 64;
    const int nl = lane & 15;
    const int q8 = lane >> 4;

    int idx = blockIdx.x;
    const int og = idx % 3; idx /= 3;
    const int v2 = idx & 127;
    const int b  = idx >> 7;
    const int v0 = v2 * 2;

    floatx4 acc[2][4];
    #pragma unroll
    for (int i = 0; i < 2; i++)
        #pragma unroll
        for (int j = 0; j < 4; j++) acc[i][j] = (floatx4)0.f;

    const int rr = tid >> 6, ts = tid & 63;
    const int vsrc = v0 - 1 + rr;
    const int ar = tid >> 2, sub = tid & 3;

    for (int cc = 0; cc < 8; cc++) {
        const int c0 = cc * 32;
        __syncthreads();
        {
            ushort* bdst = &Bs[(rr * 66 + 1 + ts) * 40];
            if (vsrc >= 0 && vsrc < V_) {
                const ushort* src = &xT[(((size_t)b * V_ + vsrc) * T_ + ts) * C_ + c0];
                *(uint4*)(bdst + 0)  = *(const uint4*)(src + 0);
                *(uint4*)(bdst + 8)  = *(const uint4*)(src + 8);
                *(uint4*)(bdst + 16) = *(const uint4*)(src + 16);
                *(uint4*)(bdst + 24) = *(const uint4*)(src + 24);
            } else {
                const uint4 z = {0u, 0u, 0u, 0u};
                *(uint4*)(bdst + 0) = z; *(uint4*)(bdst + 8) = z;
                *(uint4*)(bdst + 16) = z; *(uint4*)(bdst + 24) = z;
            }
            if (tid < 8) {
                const int r2 = tid >> 1, side = (tid & 1) * 65;
                ushort* zp = &Bs[(r2 * 66 + side) * 40];
                const uint4 z = {0u, 0u, 0u, 0u};
                *(uint4*)(zp + 0) = z; *(uint4*)(zp + 8) = z;
                *(uint4*)(zp + 16) = z; *(uint4*)(zp + 24) = z;
            }
        }
        {
            const ushort* asrc = &Wqkv[(size_t)(og * 64 + ar) * 2304 + cc * 288];
            ushort* adst = &As[ar * 296];
            #pragma unroll
            for (int j = 0; j < 9; j++) {
                const int w8 = (sub + j * 4) * 8;
                *(uint4*)(adst + w8) = *(const uint4*)(asrc + w8);
            }
        }
        __syncthreads();

        #pragma unroll
        for (int tap = 0; tap < 9; tap++) {
            const int dv = tap / 3, dt = tap % 3;
            const bf16x8 a0 = *(const bf16x8*)&As[(wave_m + nl) * 296 + tap * 32 + q8 * 8];
            const bf16x8 a1 = *(const bf16x8*)&As[(wave_m + 16 + nl) * 296 + tap * 32 + q8 * 8];
            #pragma unroll
            for (int nt = 0; nt < 4; nt++) {
                const int n0 = wave_n + nt * 16;
                const int vv = n0 >> 6, tt0 = n0 & 63;
                const bf16x8 bf = *(const bf16x8*)
                    &Bs[((vv + dv) * 66 + tt0 + nl + dt) * 40 + q8 * 8];
                acc[0][nt] = __builtin_amdgcn_mfma_f32_16x16x32_bf16(a0, bf, acc[0][nt], 0, 0, 0);
                acc[1][nt] = __builtin_amdgcn_mfma_f32_16x16x32_bf16(a1, bf, acc[1][nt], 0, 0, 0);
            }
        }
    }

    #pragma unroll
    for (int mt = 0; mt < 2; mt++) {
        const int g0 = og * 64 + wave_m + mt * 16 + q8 * 4;
        ushort* buf; int cbase, Cb;
        if (g0 < 32)      { buf = qb; cbase = g0;      Cb = CQ_; }
        else if (g0 < 64) { buf = kb; cbase = g0 - 32; Cb = CQ_; }
        else              { buf = vb; cbase = g0 - 64; Cb = C1_; }
        #pragma unroll
        for (int nt = 0; nt < 4; nt++) {
            const int n = wave_n + nt * 16 + nl;
            const int vv = n >> 6, tt = n & 63;
            const floatx4 A = acc[mt][nt];
            ushort4 o;
            o.x = f2bf(A[0]); o.y = f2bf(A[1]); o.z = f2bf(A[2]); o.w = f2bf(A[3]);
            *(ushort4*)&buf[(((size_t)b * V_ + v0 + vv) * T_ + tt) * Cb + cbase] = o;
        }
    }
}

// ---------------------------------------------------------------------------
// conv_o_mfma: unchanged from R2.
// ---------------------------------------------------------------------------
__global__ __launch_bounds__(256) void conv_o_mfma(
    const ushort* __restrict__ avT, const ushort* __restrict__ Wo,
    const float* __restrict__ x, const float* __restrict__ sigma,
    float* __restrict__ out)
{
    __shared__ __align__(16) ushort Bs[4 * 66 * 40];
    __shared__ __align__(16) ushort As[64 * 296];

    const int tid  = threadIdx.x;
    const int lane = tid & 63;
    const int wave = tid >> 6;
    const int wave_m = (wave >> 1) * 32;
    const int wave_n = (wave & 1) * 64;
    const int nl = lane & 15;
    const int q8 = lane >> 4;

    int idx = blockIdx.x;
    const int og = idx & 3; idx >>= 2;
    const int v2 = idx & 127;
    const int b  = idx >> 7;
    const int v0 = v2 * 2;

    floatx4 acc[2][4];
    #pragma unroll
    for (int i = 0; i < 2; i++)
        #pragma unroll
        for (int j = 0; j < 4; j++) acc[i][j] = (floatx4)0.f;

    const int rr = tid >> 6, ts = tid & 63;
    const int vsrc = v0 - 1 + rr;
    const int ar = tid >> 2, sub = tid & 3;

    for (int cc = 0; cc < 4; cc++) {
        const int c0 = cc * 32;
        __syncthreads();
        {
            ushort* bdst = &Bs[(rr * 66 + 1 + ts) * 40];
            if (vsrc >= 0 && vsrc < V_) {
                const ushort* src = &avT[(((size_t)b * V_ + vsrc) * T_ + ts) * C1_ + c0];
                *(uint4*)(bdst + 0)  = *(const uint4*)(src + 0);
                *(uint4*)(bdst + 8)  = *(const uint4*)(src + 8);
                *(uint4*)(bdst + 16) = *(const uint4*)(src + 16);
                *(uint4*)(bdst + 24) = *(const uint4*)(src + 24);
            } else {
                const uint4 z = {0u, 0u, 0u, 0u};
                *(uint4*)(bdst + 0) = z; *(uint4*)(bdst + 8) = z;
                *(uint4*)(bdst + 16) = z; *(uint4*)(bdst + 24) = z;
            }
            if (tid < 8) {
                const int r2 = tid >> 1, side = (tid & 1) * 65;
                ushort* zp = &Bs[(r2 * 66 + side) * 40];
                const uint4 z = {0u, 0u, 0u, 0u};
                *(uint4*)(zp + 0) = z; *(uint4*)(zp + 8) = z;
                *(uint4*)(zp + 16) = z; *(uint4*)(zp + 24) = z;
            }
        }
        {
            const ushort* asrc = &Wo[(size_t)(og * 64 + ar) * 1152 + cc * 288];
            ushort* adst = &As[ar * 296];
            #pragma unroll
            for (int j = 0; j < 9; j++) {
                const int w8 = (sub + j * 4) * 8;
                *(uint4*)(adst + w8) = *(const uint4*)(asrc + w8);
            }
        }
        __syncthreads();

        #pragma unroll
        for (int tap = 0; tap < 9; tap++) {
            const int dv = tap / 3, dt = tap % 3;
            const bf16x8 a0 = *(const bf16x8*)&As[(wave_m + nl) * 296 + tap * 32 + q8 * 8];
            const bf16x8 a1 = *(const bf16x8*)&As[(wave_m + 16 + nl) * 296 + tap * 32 + q8 * 8];
            #pragma unroll
            for (int nt = 0; nt < 4; nt++) {
                const int n0 = wave_n + nt * 16;
                const int vv = n0 >> 6, tt0 = n0 & 63;
                const bf16x8 bf = *(const bf16x8*)
                    &Bs[((vv + dv) * 66 + tt0 + nl + dt) * 40 + q8 * 8];
                acc[0][nt] = __builtin_amdgcn_mfma_f32_16x16x32_bf16(a0, bf, acc[0][nt], 0, 0, 0);
                acc[1][nt] = __builtin_amdgcn_mfma_f32_16x16x32_bf16(a1, bf, acc[1][nt], 0, 0, 0);
            }
        }
    }

    const float sg = sigma[0];
    #pragma unroll
    for (int mt = 0; mt < 2; mt++) {
        const int cb = og * 64 + wave_m + mt * 16 + q8 * 4;
        #pragma unroll
        for (int nt = 0; nt < 4; nt++) {
            const int n = wave_n + nt * 16 + nl;
            const int vv = n >> 6, tt = n & 63;
            const floatx4 A = acc[mt][nt];
            #pragma unroll
            for (int r = 0; r < 4; r++) {
                const size_t o = (((size_t)b * C_ + cb + r) * V_ + (v0 + vv)) * T_ + tt;
                out[o] = x[o] + sg * A[r];
            }
        }
    }
}

// ---------------------------------------------------------------------------
// attn_mfma: flash-style MFMA attention, one block per (b,t) slice.
// 4 waves; wave w owns v-rows [64w, 64w+64). Full K slice + V^T in LDS.
// S^T = mfma(K_frag, Q_frag) -> D[u][v]: softmax dim u is spread over
// (ut, q8, regs); the per-COLUMN (v) online stats are lane-local after two
// shfl_xor(16/32) reductions. P roundtrips via per-wave Psh (C-layout ->
// B-operand layout). PV: O^T[c][v] = mfma(Vt_frag, P_frag).
// Vt uses pad-264 rows + 16B-block XOR swizzle (block ^= (c>>3)&7): both the
// transpose-in scatter writes and the A-frag reads are ~conflict-free.
// ---------------------------------------------------------------------------
#define L2E 1.44269504f

__global__ __launch_bounds__(256, 1) void attn_mfma(
    const ushort* __restrict__ qb, const ushort* __restrict__ kb,
    const ushort* __restrict__ vb, ushort* __restrict__ avT)
{
    __shared__ __align__(16) ushort Ksh[256 * 40];     // 20.5 KB
    __shared__ __align__(16) ushort Vt[128 * 264];     // 67.6 KB (swizzled)
    __shared__ __align__(16) ushort Psh[4][64 * 72];   // 36.9 KB

    const int tid  = threadIdx.x;
    const int lane = tid & 63;
    const int w    = tid >> 6;
    const int l15  = lane & 15;
    const int q8   = lane >> 4;
    const int bt = blockIdx.x;
    const int b = bt >> 6, t = bt & 63;

    // ---- stage K slice: Ksh[u][c], row pad 40 halves ----
    {
        const ushort* kp = &kb[(((size_t)b * 256 + tid) * 64 + t) * 32];
        #pragma unroll
        for (int j = 0; j < 4; j++)
            *(uint4*)&Ksh[tid * 40 + j * 8] = *(const uint4*)(kp + j * 8);
    }
    // ---- stage V^T: Vt[c][u], 16B-u-block swizzled ----
    {
        const int c8 = tid & 15;                 // channel group of 8
        #pragma unroll
        for (int it = 0; it < 8; it++) {
            const int up = it * 16 + (tid >> 4); // u-pair 0..127
            const ushort* vp0 = &vb[(((size_t)b * 256 + up * 2) * 64 + t) * 128 + c8 * 8];
            uint4 ra = *(const uint4*)vp0;
            uint4 rb = *(const uint4*)(vp0 + 64 * 128);
            const ushort* pa = (const ushort*)&ra;
            const ushort* pb = (const ushort*)&rb;
            const int g = up >> 2, sub = up & 3;
            #pragma unroll
            for (int j = 0; j < 8; j++) {
                const int c = c8 * 8 + j;
                const uint word = (uint)pa[j] | ((uint)pb[j] << 16);
                *(uint*)((char*)(Vt + c * 264) + ((g ^ (c8 & 7)) * 16 + sub * 4)) = word;
            }
        }
    }
    // ---- Q fragments (loop-invariant) ----
    bf16x8 qf[4];
    #pragma unroll
    for (int vt = 0; vt < 4; vt++) {
        const int v = w * 64 + vt * 16 + l15;
        qf[vt] = *(const bf16x8*)&qb[(((size_t)b * 256 + v) * 64 + t) * 32 + q8 * 8];
    }
    __syncthreads();

    floatx4 accO[8][4];
    #pragma unroll
    for (int ct = 0; ct < 8; ct++)
        #pragma unroll
        for (int vt = 0; vt < 4; vt++) accO[ct][vt] = (floatx4)0.f;
    float m2[4] = {-3e38f, -3e38f, -3e38f, -3e38f};
    float lr[4] = {0.f, 0.f, 0.f, 0.f};
    ushort* Pw = Psh[w];

    for (int ch = 0; ch < 4; ch++) {
        const int u0 = ch * 64;
        // ---- S^T chunk: 16 tiles [ut][vt] ----
        floatx4 s[4][4];
        #pragma unroll
        for (int ut = 0; ut < 4; ut++) {
            const bf16x8 kf = *(const bf16x8*)&Ksh[(u0 + ut * 16 + l15) * 40 + q8 * 8];
            #pragma unroll
            for (int vt = 0; vt < 4; vt++) {
                floatx4 z = (floatx4)0.f;
                s[ut][vt] = __builtin_amdgcn_mfma_f32_16x16x32_bf16(kf, qf[vt], z, 0, 0, 0);
            }
        }
        // ---- online softmax per column v (log2 domain) ----
        #pragma unroll
        for (int vt = 0; vt < 4; vt++) {
            #pragma unroll
            for (int ut = 0; ut < 4; ut++)
                #pragma unroll
                for (int r = 0; r < 4; r++) s[ut][vt][r] *= L2E;
            float cm = -3e38f;
            #pragma unroll
            for (int ut = 0; ut < 4; ut++)
                #pragma unroll
                for (int r = 0; r < 4; r++) cm = fmaxf(cm, s[ut][vt][r]);
            cm = fmaxf(cm, __shfl_xor(cm, 16));
            cm = fmaxf(cm, __shfl_xor(cm, 32));
            const float mn = fmaxf(m2[vt], cm);
            const float alpha = __builtin_amdgcn_exp2f(m2[vt] - mn);
            float csum = 0.f;
            #pragma unroll
            for (int ut = 0; ut < 4; ut++)
                #pragma unroll
                for (int r = 0; r < 4; r++) {
                    const float p = __builtin_amdgcn_exp2f(s[ut][vt][r] - mn);
                    s[ut][vt][r] = p;
                    csum += p;
                }
            csum += __shfl_xor(csum, 16);
            csum += __shfl_xor(csum, 32);
            lr[vt] = lr[vt] * alpha + csum;
            m2[vt] = mn;
            #pragma unroll
            for (int ct = 0; ct < 8; ct++)
                #pragma unroll
                for (int r = 0; r < 4; r++) accO[ct][vt][r] *= alpha;
            // pack P -> Psh[v][u_local] (bf16)
            const int vrow = vt * 16 + l15;
            #pragma unroll
            for (int ut = 0; ut < 4; ut++) {
                const uint w01 = (uint)f2bf(s[ut][vt][0]) | ((uint)f2bf(s[ut][vt][1]) << 16);
                const uint w23 = (uint)f2bf(s[ut][vt][2]) | ((uint)f2bf(s[ut][vt][3]) << 16);
                ushort* pp = Pw + vrow * 72 + ut * 16 + q8 * 4;
                *(uint*)pp = w01;
                *(uint*)(pp + 2) = w23;
            }
        }
        // ---- PV: accO[ct][vt] += Vt_frag * P_frag ----
        #pragma unroll
        for (int kc = 0; kc < 2; kc++) {
            bf16x8 pf[4];
            #pragma unroll
            for (int vt = 0; vt < 4; vt++)
                pf[vt] = *(const bf16x8*)&Pw[(vt * 16 + l15) * 72 + kc * 32 + q8 * 8];
            #pragma unroll
            for (int ct = 0; ct < 8; ct++) {
                const int c = ct * 16 + l15;
                const int ublk = (u0 + kc * 32) / 8 + q8;
                const bf16x8 vf = *(const bf16x8*)
                    ((const char*)(Vt + c * 264) + ((ublk ^ ((c >> 3) & 7)) * 16));
                #pragma unroll
                for (int vt = 0; vt < 4; vt++)
                    accO[ct][vt] = __builtin_amdgcn_mfma_f32_16x16x32_bf16(vf, pf[vt], accO[ct][vt], 0, 0, 0);
            }
        }
    }

    // ---- epilogue: normalize, restage via Psh, coalesced 128B stores ----
    float inv[4];
    #pragma unroll
    for (int vt = 0; vt < 4; vt++) inv[vt] = 1.f / lr[vt];

    #pragma unroll
    for (int half = 0; half < 2; half++) {
        #pragma unroll
        for (int ct4 = 0; ct4 < 4; ct4++) {
            const int ct = half * 4 + ct4;
            #pragma unroll
            for (int vt = 0; vt < 4; vt++) {
                ushort4 o;
                o.x = f2bf(accO[ct][vt][0] * inv[vt]);
                o.y = f2bf(accO[ct][vt][1] * inv[vt]);
                o.z = f2bf(accO[ct][vt][2] * inv[vt]);
                o.w = f2bf(accO[ct][vt][3] * inv[vt]);
                *(ushort4*)&Pw[(vt * 16 + l15) * 72 + ct4 * 16 + q8 * 4] = o;
            }
        }
        // wave-local: lane v copies its 64-channel half-row out (128B)
        const size_t dst = (((size_t)b * 256 + w * 64 + lane) * 64 + t) * 128 + half * 64;
        #pragma unroll
        for (int j = 0; j < 8; j++)
            *(uint4*)&avT[dst + j * 8] = *(const uint4*)&Pw[lane * 72 + j * 8];
    }
}

// ---------------------------------------------------------------------------
extern "C" void kernel_launch(void* const* d_in, const int* in_sizes, int n_in,
                              void* d_out, int out_size, void* d_ws, size_t ws_size,
                              hipStream_t stream)
{
    const float* x     = (const float*)d_in[0];
    const float* wq    = (const float*)d_in[1];
    const float* wk    = (const float*)d_in[2];
    const float* wv    = (const float*)d_in[3];
    const float* wo    = (const float*)d_in[4];
    const float* sigma = (const float*)d_in[5];
    float* out = (float*)d_out;

    // workspace (bf16/ushort), total ~152.5 MB
    ushort* ws   = (ushort*)d_ws;
    ushort* xT   = ws;  ws += (size_t)B_ * V_ * T_ * C_;    // 33,554,432
    ushort* qb   = ws;  ws += (size_t)B_ * V_ * T_ * CQ_;   //  4,194,304
    ushort* kb   = ws;  ws += (size_t)B_ * V_ * T_ * CQ_;   //  4,194,304
    ushort* vb   = ws;  ws += (size_t)B_ * V_ * T_ * C1_;   // 16,777,216
    ushort* avT  = ws;  ws += (size_t)B_ * V_ * T_ * C1_;   // 16,777,216
    ushort* Wqkv = ws;  ws += 192 * 2304;
    ushort* Wo   = ws;  ws += 256 * 1152;

    transpose_x <<<B_ * V_, 256, 0, stream>>>(x, xT);
    pack_weights<<<448, 256, 0, stream>>>(wq, wk, wv, wo, Wqkv, Wo);
    conv_qkv_mfma<<<B_ * 128 * 3, 256, 0, stream>>>(xT, Wqkv, qb, kb, vb);
    attn_mfma   <<<B_ * T_, 256, 0, stream>>>(qb, kb, vb, avT);
    conv_o_mfma <<<B_ * 128 * 4, 256, 0, stream>>>(avT, Wo, x, sigma, out);
}